// Round 12
// baseline (1616.948 us; speedup 1.0000x reference)
//
#include <hip/hip_runtime.h>
#include <hip/hip_bf16.h>
#include <cstdint>
#include <cstddef>

typedef __attribute__((ext_vector_type(8))) short bf16x8;
typedef __attribute__((ext_vector_type(4))) float f32x4;
typedef __attribute__((ext_vector_type(16))) float f32x16;

constexpr int CL = 4;      // layers
constexpr int CS = 512;    // seq len

// fp32 -> bf16 RNE via HIP intrinsic (1 VALU op vs 5 for the software round)
__device__ __forceinline__ short f2bf(float f) {
  union { __hip_bfloat16 h; short s; } u;
  u.h = __float2bfloat16(f);
  return u.s;
}
__device__ __forceinline__ uint32_t pk2bf(float a, float b) {
  return (uint32_t)(uint16_t)f2bf(a) | ((uint32_t)(uint16_t)f2bf(b) << 16);
}
__device__ __forceinline__ f32x16 mfma32(bf16x8 a, bf16x8 b, f32x16 c) {
  return __builtin_amdgcn_mfma_f32_32x32x16_bf16(a, b, c, 0, 0, 0);
}
__device__ __forceinline__ f32x16 zero16() {
  f32x16 z;
#pragma unroll
  for (int i = 0; i < 16; ++i) z[i] = 0.f;
  return z;
}
// XOR swizzle: conflict-free for 32-row column-slice ds_read_b128.
__device__ __forceinline__ int swzW(int r, int c, int ldshift) {
  int g = (c >> 3) ^ (r & 7) ^ (((r >> 3) & 3) << 3);
  return (r << ldshift) + (g << 3) + (c & 7);
}

__global__ void cvt_bf16(const float* __restrict__ src, short* __restrict__ dst, int n) {
  int i = blockIdx.x * blockDim.x + threadIdx.x;
  int stride = gridDim.x * blockDim.x;
  for (; i < n; i += stride) dst[i] = f2bf(src[i]);
}

// B-fragment for mfma_f32_32x32x16 from row-major [N][K] weights.
template<int USEWS>
__device__ __forceinline__ bf16x8 ldB32(const short* __restrict__ wb,
                                        const float* __restrict__ wf,
                                        int ldk, int n0, int k0, int lane) {
  int n = n0 + (lane & 31);
  int k = k0 + ((lane >> 5) << 3);
  if constexpr (USEWS) {
    return *(const bf16x8*)&wb[(size_t)n * ldk + k];
  } else {
    const float* p = &wf[(size_t)n * ldk + k];
    f32x4 u = *(const f32x4*)p;
    f32x4 v = *(const f32x4*)(p + 4);
    bf16x8 r;
    r[0]=f2bf(u[0]); r[1]=f2bf(u[1]); r[2]=f2bf(u[2]); r[3]=f2bf(u[3]);
    r[4]=f2bf(v[0]); r[5]=f2bf(v[1]); r[6]=f2bf(v[2]); r[7]=f2bf(v[3]);
    return r;
  }
}

#define CROW(reg) ((((reg) & 3)) + ((((reg) >> 2)) << 3) + (hi << 2))

template<int USEWS>
__global__ __launch_bounds__(512, 2)
void swt_fused(const float* __restrict__ X,
               const float* __restrict__ pos,
               const float* __restrict__ wqf, const float* __restrict__ bq_all,
               const float* __restrict__ wof, const float* __restrict__ bo_all,
               const float* __restrict__ w1f, const float* __restrict__ b1_all,
               const float* __restrict__ w2f, const float* __restrict__ b2_all,
               const float* __restrict__ g1_all, const float* __restrict__ be1_all,
               const float* __restrict__ g2_all, const float* __restrict__ be2_all,
               const float* __restrict__ hw, const float* __restrict__ hb,
               const short* __restrict__ wqb, const short* __restrict__ wob,
               const short* __restrict__ w1b, const short* __restrict__ w2b,
               float* __restrict__ out)
{
  __shared__ __align__(16) char arena[139776];
  short* xb = (short*)arena;                   // [64][256] swz bf16 x (both windows)
  short* qS = (short*)(arena + 32768);         // [64][256] swz : q
  short* kS = (short*)(arena + 65536);         // [64][256] swz : k -> o
  short* vt = (short*)(arena + 98304);         // [16][32][38] v^T per (win,head)
  float* lnM = (float*)(arena + 137216);       // [64][2] mu/rs
  float* hf  = (float*)(arena + 137728);       // [2][256] head input
  float* lnbuf = (float*)(arena + 32768);      // [64][260] overlay (LN dump / phase0)
  short* kb = (short*)(arena + 32768);         // [64][512] swz overlay (FFN hidden)

  const int tid = threadIdx.x;
  const int wv = tid >> 6;            // 0..7 = column octant
  const int lane = tid & 63;
  const int l31 = lane & 31;
  const int hi = lane >> 5;

  const int blk = blockIdx.x;

  // ---------- phase 0: build 2 windows (x + pos) ----------
  {
    int r = tid >> 3;                 // 0..63
    int c0 = (tid & 7) << 5;          // 32 floats per thread
    int wi0 = r >> 5, slot = r & 31;
    int g = (blk << 1) + wi0;
    int bb = g >> 9, ss = g & (CS - 1);
    int src = ss - slot; if (src < 0) src = 0;
    const float* Xr = X + (((size_t)(bb * CS + src)) << 8) + c0;
    const float* Pr = pos + (slot << 8) + c0;
#pragma unroll
    for (int m = 0; m < 4; ++m) {
      f32x4 x0 = *(const f32x4*)(Xr + m * 8);
      f32x4 x1 = *(const f32x4*)(Xr + m * 8 + 4);
      f32x4 p0 = *(const f32x4*)(Pr + m * 8);
      f32x4 p1 = *(const f32x4*)(Pr + m * 8 + 4);
      f32x4 s0, s1;
      bf16x8 pkv;
#pragma unroll
      for (int j = 0; j < 4; ++j) { s0[j] = x0[j] + p0[j]; pkv[j] = f2bf(s0[j]); }
#pragma unroll
      for (int j = 0; j < 4; ++j) { s1[j] = x1[j] + p1[j]; pkv[4 + j] = f2bf(s1[j]); }
      *(f32x4*)&lnbuf[r * 260 + c0 + m * 8] = s0;
      *(f32x4*)&lnbuf[r * 260 + c0 + m * 8 + 4] = s1;
      *(bf16x8*)&xb[swzW(r, c0 + m * 8, 8)] = pkv;
    }
  }
  __syncthreads();

  // residual registers for BOTH windows: win0 rows CROW, win1 rows 32+CROW; col 32*wv+l31
  f32x16 rs0, rs1;
  {
    int c = (wv << 5) + l31;
#pragma unroll
    for (int reg = 0; reg < 16; ++reg) {
      rs0[reg] = lnbuf[(CROW(reg)) * 260 + c];
      rs1[reg] = lnbuf[(32 + CROW(reg)) * 260 + c];
    }
  }
  __syncthreads();

  // Hoisted xb A-fragments: Axb[2k] = win0 step k, Axb[2k+1] = win1 step k.
  // All indexing compile-time (full unroll) so they stay in VGPRs.
  bf16x8 Axb[32];
  auto loadAxb = [&]() {
#pragma unroll
    for (int kk = 0; kk < 16; ++kk) {
      Axb[2 * kk]     = *(const bf16x8*)&xb[swzW(l31,      (kk << 4) + (hi << 3), 8)];
      Axb[2 * kk + 1] = *(const bf16x8*)&xb[swzW(32 + l31, (kk << 4) + (hi << 3), 8)];
    }
  };
  // gemm from hoisted A (xb): no LDS reads, 1 B-load + 2 mfma per step
  auto gemmDualA = [&](const short* wb, const float* wf, int ldk,
                       int bn0, f32x16& acc0, f32x16& acc1) {
#pragma unroll
    for (int kk = 0; kk < 16; ++kk) {
      bf16x8 B = ldB32<USEWS>(wb, wf, ldk, bn0, kk << 4, lane);
      acc0 = mfma32(Axb[2 * kk],     B, acc0);
      acc1 = mfma32(Axb[2 * kk + 1], B, acc1);
    }
  };
  // transient-A gemm (kS / kb sources)
  auto gemmDual = [&](const short* Abuf, int ldshift,
                      const short* wb, const float* wf, int ldk,
                      int bn0, int kB, int nsteps, f32x16& acc0, f32x16& acc1) {
#pragma unroll 4
    for (int kk = 0; kk < nsteps; ++kk) {
      bf16x8 A0 = *(const bf16x8*)&Abuf[swzW(l31,      (kk << 4) + (hi << 3), ldshift)];
      bf16x8 A1 = *(const bf16x8*)&Abuf[swzW(32 + l31, (kk << 4) + (hi << 3), ldshift)];
      bf16x8 B = ldB32<USEWS>(wb, wf, ldk, bn0, kB + (kk << 4), lane);
      acc0 = mfma32(A0, B, acc0);
      acc1 = mfma32(A1, B, acc1);
    }
  };

  auto lnorm = [&](const float* g, const float* be) {
    int c = (wv << 5) + l31;
#pragma unroll
    for (int reg = 0; reg < 16; ++reg) {
      lnbuf[(CROW(reg)) * 260 + c]      = rs0[reg];
      lnbuf[(32 + CROW(reg)) * 260 + c] = rs1[reg];
    }
    __syncthreads();
    {
      int r = tid >> 3, sub = tid & 7;
      float s1 = 0.f, s2 = 0.f;
#pragma unroll
      for (int i = 0; i < 32; ++i) {
        float v = lnbuf[r * 260 + sub + (i << 3)];
        s1 += v; s2 += v * v;
      }
#pragma unroll
      for (int d = 1; d < 8; d <<= 1) { s1 += __shfl_xor(s1, d); s2 += __shfl_xor(s2, d); }
      if (sub == 0) {
        float mu = s1 * (1.f / 256.f);
        float var = s2 * (1.f / 256.f) - mu * mu;
        lnM[r * 2] = mu;
        lnM[r * 2 + 1] = rsqrtf(var + 1e-5f);
      }
    }
    __syncthreads();
    {
      float gv = g[c], bv = be[c];
#pragma unroll
      for (int reg = 0; reg < 16; ++reg) {
        int R0 = CROW(reg), R1 = 32 + R0;
        float v0 = (rs0[reg] - lnM[R0 * 2]) * lnM[R0 * 2 + 1] * gv + bv;
        float v1 = (rs1[reg] - lnM[R1 * 2]) * lnM[R1 * 2 + 1] * gv + bv;
        rs0[reg] = v0;
        rs1[reg] = v1;
        xb[swzW(R0, c, 8)] = f2bf(v0);
        xb[swzW(R1, c, 8)] = f2bf(v1);
      }
    }
    __syncthreads();
  };

  const float scale = 0.17677669529663687f;  // 1/sqrt(32)

#pragma unroll 1
  for (int l = 0; l < CL; ++l) {
    const short* wqb_l = wqb + (size_t)l * 768 * 256;
    const float* wqf_l = wqf + (size_t)l * 768 * 256;
    const float* bq_l  = bq_all + l * 768;
    const short* wob_l = wob + (size_t)l * 256 * 256;
    const float* wof_l = wof + (size_t)l * 256 * 256;
    const float* bo_l  = bo_all + l * 256;
    const short* w1b_l = w1b + (size_t)l * 1024 * 256;
    const float* w1f_l = w1f + (size_t)l * 1024 * 256;
    const float* b1_l  = b1_all + l * 1024;
    const short* w2b_l = w2b + (size_t)l * 256 * 1024;
    const float* w2f_l = w2f + (size_t)l * 256 * 1024;
    const float* b2_l  = b2_all + l * 256;

    // ---------- QKV: 3 rounds, tile t = r*8 + wv; A from registers ----------
    loadAxb();
#pragma unroll 1
    for (int r = 0; r < 3; ++r) {
      int t = r * 8 + wv;                     // 0..23
      f32x16 a0 = zero16(), a1 = zero16();
      gemmDualA(wqb_l, wqf_l, 256, t << 5, a0, a1);
      float bv = bq_l[(t << 5) + l31];
      if (t < 8) {                            // q (pre-scaled)
        int col = (t << 5) + l31;
#pragma unroll
        for (int reg = 0; reg < 16; ++reg) {
          qS[swzW(CROW(reg), col, 8)]      = f2bf((a0[reg] + bv) * scale);
          qS[swzW(32 + CROW(reg), col, 8)] = f2bf((a1[reg] + bv) * scale);
        }
      } else if (t < 16) {                    // k
        int col = ((t - 8) << 5) + l31;
#pragma unroll
        for (int reg = 0; reg < 16; ++reg) {
          kS[swzW(CROW(reg), col, 8)]      = f2bf(a0[reg] + bv);
          kS[swzW(32 + CROW(reg), col, 8)] = f2bf(a1[reg] + bv);
        }
      } else {                                // v -> v^T per (win, head)
        int h = t - 16;
        short* vr0 = &vt[((size_t)(h)     * 32 + l31) * 38];
        short* vr1 = &vt[((size_t)(8 + h) * 32 + l31) * 38];
#pragma unroll
        for (int reg = 0; reg < 16; ++reg) {
          vr0[CROW(reg)] = f2bf(a0[reg] + bv);
          vr1[CROW(reg)] = f2bf(a1[reg] + bv);
        }
      }
    }
    __syncthreads();

    // ---------- attention: head = wv, both windows ----------
#pragma unroll
    for (int wi2 = 0; wi2 < 2; ++wi2) {
      int ar = wi2 << 5;
      int hc = wv << 5;
      f32x16 st = zero16();
#pragma unroll
      for (int ks = 0; ks < 2; ++ks) {
        bf16x8 ak = *(const bf16x8*)&kS[swzW(ar + l31, hc + (ks << 4) + (hi << 3), 8)];
        bf16x8 bq_ = *(const bf16x8*)&qS[swzW(ar + l31, hc + (ks << 4) + (hi << 3), 8)];
        st = mfma32(ak, bq_, st);   // S^T[tok][q]
      }
      float m = st[0];
#pragma unroll
      for (int reg = 1; reg < 16; ++reg) m = fmaxf(m, st[reg]);
      m = fmaxf(m, __shfl_xor(m, 32));
      float s = 0.f;
#pragma unroll
      for (int reg = 0; reg < 16; ++reg) { st[reg] = __expf(st[reg] - m); s += st[reg]; }
      s += __shfl_xor(s, 32);
      float inv = 1.0f / s;
#pragma unroll
      for (int reg = 0; reg < 16; ++reg) st[reg] *= inv;

      f32x16 ot = zero16();
#pragma unroll
      for (int ks = 0; ks < 2; ++ks) {
        uint32_t a0 = pk2bf(st[ks * 8 + 0], st[ks * 8 + 1]);
        uint32_t a1 = pk2bf(st[ks * 8 + 2], st[ks * 8 + 3]);
        uint32_t b0 = pk2bf(st[ks * 8 + 4], st[ks * 8 + 5]);
        uint32_t b1 = pk2bf(st[ks * 8 + 6], st[ks * 8 + 7]);
        uint32_t sa0 = __shfl_xor(a0, 32);
        uint32_t sa1 = __shfl_xor(a1, 32);
        uint32_t sb0 = __shfl_xor(b0, 32);
        uint32_t sb1 = __shfl_xor(b1, 32);
        union { uint32_t u[4]; bf16x8 v; } pf;
        pf.u[0] = hi ? sb0 : a0;
        pf.u[1] = hi ? sb1 : a1;
        pf.u[2] = hi ? b0 : sa0;
        pf.u[3] = hi ? b1 : sa1;
        bf16x8 av = *(const bf16x8*)&vt[(((wi2 << 3) + wv) * 32 + l31) * 38 + (ks << 4) + (hi << 3)];
        ot = mfma32(av, pf.v, ot);  // O^T[dh][q]
      }
#pragma unroll
      for (int reg = 0; reg < 16; ++reg)
        kS[swzW(ar + l31, hc + CROW(reg), 8)] = f2bf(ot[reg]);
    }
    __syncthreads();

    // ---------- output projection: tile wv, both windows, K=256 ----------
    {
      f32x16 a0 = zero16(), a1 = zero16();
      gemmDual(kS, 8, wob_l, wof_l, 256, wv << 5, 0, 16, a0, a1);
      float bv = bo_l[(wv << 5) + l31];
#pragma unroll
      for (int reg = 0; reg < 16; ++reg) {
        rs0[reg] += a0[reg] + bv;
        rs1[reg] += a1[reg] + bv;
      }
    }
    __syncthreads();               // kS/qS reads retired before lnbuf overlay
    lnorm(g1_all + (l << 8), be1_all + (l << 8));

    // ---------- FFN: 2 chunks of 512 hidden; A (xb) hoisted across both ----------
    loadAxb();
    {
#pragma unroll 1
      for (int ch = 0; ch < 2; ++ch) {
        // FFN1: 2 rounds, hidden tile t = r*8 + wv of this chunk, A from registers
#pragma unroll 1
        for (int r = 0; r < 2; ++r) {
          int t = r * 8 + wv;                 // 0..15
          f32x16 h0 = zero16(), h1 = zero16();
          int ng = (ch << 9) + (t << 5);
          gemmDualA(w1b_l, w1f_l, 256, ng, h0, h1);
          float bv1 = b1_l[ng + l31];
          int hcol = (t << 5) + l31;
#pragma unroll
          for (int reg = 0; reg < 16; ++reg) {
            kb[swzW(CROW(reg), hcol, 9)]      = f2bf(fmaxf(h0[reg] + bv1, 0.f));
            kb[swzW(32 + CROW(reg), hcol, 9)] = f2bf(fmaxf(h1[reg] + bv1, 0.f));
          }
        }
        __syncthreads();
        // FFN2: tile wv, both windows, K=512 of this chunk, into resid
        {
          f32x16 f0 = zero16(), f1 = zero16();
          gemmDual(kb, 9, w2b_l, w2f_l, 1024, wv << 5, ch << 9, 32, f0, f1);
#pragma unroll
          for (int reg = 0; reg < 16; ++reg) {
            rs0[reg] += f0[reg];
            rs1[reg] += f1[reg];
          }
        }
        __syncthreads();                      // kb reads retired before next write
      }
      float bv2 = b2_l[(wv << 5) + l31];
#pragma unroll
      for (int reg = 0; reg < 16; ++reg) { rs0[reg] += bv2; rs1[reg] += bv2; }
    }
    lnorm(g2_all + (l << 8), be2_all + (l << 8));
  }

  // ---------- head: logits from row 31 of each window ----------
  if (hi == 1) {
    int c = (wv << 5) + l31;
    hf[c]       = rs0[15];   // CROW(15)|hi=1 == row 31
    hf[256 + c] = rs1[15];
  }
  __syncthreads();
  if (wv < 2) {
    int c = l31;
    const float* hrow = hf + (wv << 8) + (hi << 7);
    const float* wrow = hw + (c << 8) + (hi << 7);
    float sum = 0.f;
#pragma unroll
    for (int i = 0; i < 128; i += 4) {
      f32x4 a = *(const f32x4*)(hrow + i);
      f32x4 b = *(const f32x4*)(wrow + i);
      sum += a[0]*b[0] + a[1]*b[1] + a[2]*b[2] + a[3]*b[3];
    }
    sum += __shfl_xor(sum, 32);
    if (hi == 0) out[(((size_t)blk * 2 + wv) << 5) + c] = sum + hb[c];
  }
}

extern "C" void kernel_launch(void* const* d_in, const int* in_sizes, int n_in,
                              void* d_out, int out_size, void* d_ws, size_t ws_size,
                              hipStream_t stream) {
  const float* X    = (const float*)d_in[0];
  const float* pos  = (const float*)d_in[3];
  const float* wq   = (const float*)d_in[4];
  const float* bq   = (const float*)d_in[5];
  const float* wo   = (const float*)d_in[6];
  const float* bo   = (const float*)d_in[7];
  const float* w1   = (const float*)d_in[8];
  const float* b1   = (const float*)d_in[9];
  const float* w2   = (const float*)d_in[10];
  const float* b2   = (const float*)d_in[11];
  const float* g1   = (const float*)d_in[12];
  const float* be1  = (const float*)d_in[13];
  const float* g2   = (const float*)d_in[14];
  const float* be2  = (const float*)d_in[15];
  const float* hw   = (const float*)d_in[16];
  const float* hb   = (const float*)d_in[17];
  float* out = (float*)d_out;

  const size_t nq = (size_t)CL * 768 * 256;
  const size_t no = (size_t)CL * 256 * 256;
  const size_t n1 = (size_t)CL * 1024 * 256;
  const size_t n2 = (size_t)CL * 256 * 1024;
  const size_t need = (nq + no + n1 + n2) * sizeof(short);

  short* wsq = (short*)d_ws;
  short* wso = wsq + nq;
  short* ws1 = wso + no;
  short* ws2 = ws1 + n1;

  const int nblk = 1024;   // 2048 windows / 2 per block

  if (ws_size >= need) {
    cvt_bf16<<<1024, 256, 0, stream>>>(wq, wsq, (int)nq);
    cvt_bf16<<<1024, 256, 0, stream>>>(wo, wso, (int)no);
    cvt_bf16<<<1024, 256, 0, stream>>>(w1, ws1, (int)n1);
    cvt_bf16<<<1024, 256, 0, stream>>>(w2, ws2, (int)n2);
    swt_fused<1><<<nblk, 512, 0, stream>>>(X, pos, wq, bq, wo, bo, w1, b1, w2, b2,
                                           g1, be1, g2, be2, hw, hb,
                                           wsq, wso, ws1, ws2, out);
  } else {
    swt_fused<0><<<nblk, 512, 0, stream>>>(X, pos, wq, bq, wo, bo, w1, b1, w2, b2,
                                           g1, be1, g2, be2, hw, hb,
                                           nullptr, nullptr, nullptr, nullptr, out);
  }
}

// Round 13
// 1019.060 us; speedup vs baseline: 1.5867x; 1.5867x over previous
//
#include <hip/hip_runtime.h>
#include <hip/hip_bf16.h>
#include <cstdint>
#include <cstddef>

typedef __attribute__((ext_vector_type(8))) short bf16x8;
typedef __attribute__((ext_vector_type(4))) float f32x4;
typedef __attribute__((ext_vector_type(16))) float f32x16;

constexpr int CL = 4;      // layers
constexpr int CS = 512;    // seq len

// fp32 -> bf16 RNE via HIP intrinsic (1 VALU op; correctness-verified r12)
__device__ __forceinline__ short f2bf(float f) {
  union { __hip_bfloat16 h; short s; } u;
  u.h = __float2bfloat16(f);
  return u.s;
}
__device__ __forceinline__ uint32_t pk2bf(float a, float b) {
  return (uint32_t)(uint16_t)f2bf(a) | ((uint32_t)(uint16_t)f2bf(b) << 16);
}
__device__ __forceinline__ f32x16 mfma32(bf16x8 a, bf16x8 b, f32x16 c) {
  return __builtin_amdgcn_mfma_f32_32x32x16_bf16(a, b, c, 0, 0, 0);
}
__device__ __forceinline__ f32x16 zero16() {
  f32x16 z;
#pragma unroll
  for (int i = 0; i < 16; ++i) z[i] = 0.f;
  return z;
}
// XOR swizzle: conflict-free for 32-row column-slice ds_read_b128.
__device__ __forceinline__ int swzW(int r, int c, int ldshift) {
  int g = (c >> 3) ^ (r & 7) ^ (((r >> 3) & 3) << 3);
  return (r << ldshift) + (g << 3) + (c & 7);
}

__global__ void cvt_bf16(const float* __restrict__ src, short* __restrict__ dst, int n) {
  int i = blockIdx.x * blockDim.x + threadIdx.x;
  int stride = gridDim.x * blockDim.x;
  for (; i < n; i += stride) dst[i] = f2bf(src[i]);
}

// B-fragment for mfma_f32_32x32x16 from row-major [N][K] weights.
template<int USEWS>
__device__ __forceinline__ bf16x8 ldB32(const short* __restrict__ wb,
                                        const float* __restrict__ wf,
                                        int ldk, int n0, int k0, int lane) {
  int n = n0 + (lane & 31);
  int k = k0 + ((lane >> 5) << 3);
  if constexpr (USEWS) {
    return *(const bf16x8*)&wb[(size_t)n * ldk + k];
  } else {
    const float* p = &wf[(size_t)n * ldk + k];
    f32x4 u = *(const f32x4*)p;
    f32x4 v = *(const f32x4*)(p + 4);
    bf16x8 r;
    r[0]=f2bf(u[0]); r[1]=f2bf(u[1]); r[2]=f2bf(u[2]); r[3]=f2bf(u[3]);
    r[4]=f2bf(v[0]); r[5]=f2bf(v[1]); r[6]=f2bf(v[2]); r[7]=f2bf(v[3]);
    return r;
  }
}

#define CROW(reg) ((((reg) & 3)) + ((((reg) >> 2)) << 3) + (hi << 2))

template<int USEWS>
__global__ __launch_bounds__(512, 2)
void swt_fused(const float* __restrict__ X,
               const float* __restrict__ pos,
               const float* __restrict__ wqf, const float* __restrict__ bq_all,
               const float* __restrict__ wof, const float* __restrict__ bo_all,
               const float* __restrict__ w1f, const float* __restrict__ b1_all,
               const float* __restrict__ w2f, const float* __restrict__ b2_all,
               const float* __restrict__ g1_all, const float* __restrict__ be1_all,
               const float* __restrict__ g2_all, const float* __restrict__ be2_all,
               const float* __restrict__ hw, const float* __restrict__ hb,
               const short* __restrict__ wqb, const short* __restrict__ wob,
               const short* __restrict__ w1b, const short* __restrict__ w2b,
               float* __restrict__ out)
{
  __shared__ __align__(16) char arena[139776];
  short* xb = (short*)arena;                   // [64][256] swz bf16 x (both windows)
  short* qS = (short*)(arena + 32768);         // [64][256] swz : q
  short* kS = (short*)(arena + 65536);         // [64][256] swz : k -> o
  short* vt = (short*)(arena + 98304);         // [16][32][38] v^T per (win,head)
  float* lnM = (float*)(arena + 137216);       // [64][2] mu/rs
  float* hf  = (float*)(arena + 137728);       // [2][256] head input
  float* lnbuf = (float*)(arena + 32768);      // [64][260] overlay (LN dump / phase0)
  short* kb = (short*)(arena + 32768);         // [64][512] swz overlay (FFN hidden)

  const int tid = threadIdx.x;
  const int wv = tid >> 6;            // 0..7 = column octant
  const int lane = tid & 63;
  const int l31 = lane & 31;
  const int hi = lane >> 5;

  const int blk = blockIdx.x;

  // ---------- phase 0: build 2 windows (x + pos) ----------
  {
    int r = tid >> 3;                 // 0..63
    int c0 = (tid & 7) << 5;          // 32 floats per thread
    int wi0 = r >> 5, slot = r & 31;
    int g = (blk << 1) + wi0;
    int bb = g >> 9, ss = g & (CS - 1);
    int src = ss - slot; if (src < 0) src = 0;
    const float* Xr = X + (((size_t)(bb * CS + src)) << 8) + c0;
    const float* Pr = pos + (slot << 8) + c0;
#pragma unroll
    for (int m = 0; m < 4; ++m) {
      f32x4 x0 = *(const f32x4*)(Xr + m * 8);
      f32x4 x1 = *(const f32x4*)(Xr + m * 8 + 4);
      f32x4 p0 = *(const f32x4*)(Pr + m * 8);
      f32x4 p1 = *(const f32x4*)(Pr + m * 8 + 4);
      f32x4 s0, s1;
      bf16x8 pkv;
#pragma unroll
      for (int j = 0; j < 4; ++j) { s0[j] = x0[j] + p0[j]; pkv[j] = f2bf(s0[j]); }
#pragma unroll
      for (int j = 0; j < 4; ++j) { s1[j] = x1[j] + p1[j]; pkv[4 + j] = f2bf(s1[j]); }
      *(f32x4*)&lnbuf[r * 260 + c0 + m * 8] = s0;
      *(f32x4*)&lnbuf[r * 260 + c0 + m * 8 + 4] = s1;
      *(bf16x8*)&xb[swzW(r, c0 + m * 8, 8)] = pkv;
    }
  }
  __syncthreads();

  // residual registers for BOTH windows: win0 rows CROW, win1 rows 32+CROW; col 32*wv+l31
  f32x16 rs0, rs1;
  {
    int c = (wv << 5) + l31;
#pragma unroll
    for (int reg = 0; reg < 16; ++reg) {
      rs0[reg] = lnbuf[(CROW(reg)) * 260 + c];
      rs1[reg] = lnbuf[(32 + CROW(reg)) * 260 + c];
    }
  }
  __syncthreads();

  // dual-window gemm: 2 mfma per B-load (A rows l31 and 32+l31), 8-deep in-flight B
  auto gemmDual = [&](const short* Abuf, int ldshift,
                      const short* wb, const float* wf, int ldk,
                      int bn0, int kB, int nsteps, f32x16& acc0, f32x16& acc1) {
#pragma unroll 8
    for (int kk = 0; kk < nsteps; ++kk) {
      bf16x8 A0 = *(const bf16x8*)&Abuf[swzW(l31,      (kk << 4) + (hi << 3), ldshift)];
      bf16x8 A1 = *(const bf16x8*)&Abuf[swzW(32 + l31, (kk << 4) + (hi << 3), ldshift)];
      bf16x8 B = ldB32<USEWS>(wb, wf, ldk, bn0, kB + (kk << 4), lane);
      acc0 = mfma32(A0, B, acc0);
      acc1 = mfma32(A1, B, acc1);
    }
  };

  auto lnorm = [&](const float* g, const float* be) {
    int c = (wv << 5) + l31;
#pragma unroll
    for (int reg = 0; reg < 16; ++reg) {
      lnbuf[(CROW(reg)) * 260 + c]      = rs0[reg];
      lnbuf[(32 + CROW(reg)) * 260 + c] = rs1[reg];
    }
    __syncthreads();
    {
      int r = tid >> 3, sub = tid & 7;
      float s1 = 0.f, s2 = 0.f;
#pragma unroll
      for (int i = 0; i < 32; ++i) {
        float v = lnbuf[r * 260 + sub + (i << 3)];
        s1 += v; s2 += v * v;
      }
#pragma unroll
      for (int d = 1; d < 8; d <<= 1) { s1 += __shfl_xor(s1, d); s2 += __shfl_xor(s2, d); }
      if (sub == 0) {
        float mu = s1 * (1.f / 256.f);
        float var = s2 * (1.f / 256.f) - mu * mu;
        lnM[r * 2] = mu;
        lnM[r * 2 + 1] = rsqrtf(var + 1e-5f);
      }
    }
    __syncthreads();
    {
      float gv = g[c], bv = be[c];
#pragma unroll
      for (int reg = 0; reg < 16; ++reg) {
        int R0 = CROW(reg), R1 = 32 + R0;
        float v0 = (rs0[reg] - lnM[R0 * 2]) * lnM[R0 * 2 + 1] * gv + bv;
        float v1 = (rs1[reg] - lnM[R1 * 2]) * lnM[R1 * 2 + 1] * gv + bv;
        rs0[reg] = v0;
        rs1[reg] = v1;
        xb[swzW(R0, c, 8)] = f2bf(v0);
        xb[swzW(R1, c, 8)] = f2bf(v1);
      }
    }
    __syncthreads();
  };

  const float scale = 0.17677669529663687f;  // 1/sqrt(32)

#pragma unroll 1
  for (int l = 0; l < CL; ++l) {
    const short* wqb_l = wqb + (size_t)l * 768 * 256;
    const float* wqf_l = wqf + (size_t)l * 768 * 256;
    const float* bq_l  = bq_all + l * 768;
    const short* wob_l = wob + (size_t)l * 256 * 256;
    const float* wof_l = wof + (size_t)l * 256 * 256;
    const float* bo_l  = bo_all + l * 256;
    const short* w1b_l = w1b + (size_t)l * 1024 * 256;
    const float* w1f_l = w1f + (size_t)l * 1024 * 256;
    const float* b1_l  = b1_all + l * 1024;
    const short* w2b_l = w2b + (size_t)l * 256 * 1024;
    const float* w2f_l = w2f + (size_t)l * 256 * 1024;
    const float* b2_l  = b2_all + l * 256;

    // ---------- QKV: 3 rounds, tile t = r*8 + wv, both windows per job ----------
#pragma unroll 1
    for (int r = 0; r < 3; ++r) {
      int t = r * 8 + wv;                     // 0..23
      f32x16 a0 = zero16(), a1 = zero16();
      gemmDual(xb, 8, wqb_l, wqf_l, 256, t << 5, 0, 16, a0, a1);
      float bv = bq_l[(t << 5) + l31];
      if (t < 8) {                            // q (pre-scaled)
        int col = (t << 5) + l31;
#pragma unroll
        for (int reg = 0; reg < 16; ++reg) {
          qS[swzW(CROW(reg), col, 8)]      = f2bf((a0[reg] + bv) * scale);
          qS[swzW(32 + CROW(reg), col, 8)] = f2bf((a1[reg] + bv) * scale);
        }
      } else if (t < 16) {                    // k
        int col = ((t - 8) << 5) + l31;
#pragma unroll
        for (int reg = 0; reg < 16; ++reg) {
          kS[swzW(CROW(reg), col, 8)]      = f2bf(a0[reg] + bv);
          kS[swzW(32 + CROW(reg), col, 8)] = f2bf(a1[reg] + bv);
        }
      } else {                                // v -> v^T per (win, head)
        int h = t - 16;
        short* vr0 = &vt[((size_t)(h)     * 32 + l31) * 38];
        short* vr1 = &vt[((size_t)(8 + h) * 32 + l31) * 38];
#pragma unroll
        for (int reg = 0; reg < 16; ++reg) {
          vr0[CROW(reg)] = f2bf(a0[reg] + bv);
          vr1[CROW(reg)] = f2bf(a1[reg] + bv);
        }
      }
    }
    __syncthreads();

    // ---------- attention: head = wv, both windows (interleaved chains) ----------
#pragma unroll
    for (int wi2 = 0; wi2 < 2; ++wi2) {
      int ar = wi2 << 5;
      int hc = wv << 5;
      f32x16 st = zero16();
#pragma unroll
      for (int ks = 0; ks < 2; ++ks) {
        bf16x8 ak = *(const bf16x8*)&kS[swzW(ar + l31, hc + (ks << 4) + (hi << 3), 8)];
        bf16x8 bq_ = *(const bf16x8*)&qS[swzW(ar + l31, hc + (ks << 4) + (hi << 3), 8)];
        st = mfma32(ak, bq_, st);   // S^T[tok][q]
      }
      float m = st[0];
#pragma unroll
      for (int reg = 1; reg < 16; ++reg) m = fmaxf(m, st[reg]);
      m = fmaxf(m, __shfl_xor(m, 32));
      float s = 0.f;
#pragma unroll
      for (int reg = 0; reg < 16; ++reg) { st[reg] = __expf(st[reg] - m); s += st[reg]; }
      s += __shfl_xor(s, 32);
      float inv = 1.0f / s;
#pragma unroll
      for (int reg = 0; reg < 16; ++reg) st[reg] *= inv;

      f32x16 ot = zero16();
#pragma unroll
      for (int ks = 0; ks < 2; ++ks) {
        uint32_t a0 = pk2bf(st[ks * 8 + 0], st[ks * 8 + 1]);
        uint32_t a1 = pk2bf(st[ks * 8 + 2], st[ks * 8 + 3]);
        uint32_t b0 = pk2bf(st[ks * 8 + 4], st[ks * 8 + 5]);
        uint32_t b1 = pk2bf(st[ks * 8 + 6], st[ks * 8 + 7]);
        uint32_t sa0 = __shfl_xor(a0, 32);
        uint32_t sa1 = __shfl_xor(a1, 32);
        uint32_t sb0 = __shfl_xor(b0, 32);
        uint32_t sb1 = __shfl_xor(b1, 32);
        union { uint32_t u[4]; bf16x8 v; } pf;
        pf.u[0] = hi ? sb0 : a0;
        pf.u[1] = hi ? sb1 : a1;
        pf.u[2] = hi ? b0 : sa0;
        pf.u[3] = hi ? b1 : sa1;
        bf16x8 av = *(const bf16x8*)&vt[(((wi2 << 3) + wv) * 32 + l31) * 38 + (ks << 4) + (hi << 3)];
        ot = mfma32(av, pf.v, ot);  // O^T[dh][q]
      }
#pragma unroll
      for (int reg = 0; reg < 16; ++reg)
        kS[swzW(ar + l31, hc + CROW(reg), 8)] = f2bf(ot[reg]);
    }
    __syncthreads();

    // ---------- output projection: tile wv, both windows, K=256 ----------
    {
      f32x16 a0 = zero16(), a1 = zero16();
      gemmDual(kS, 8, wob_l, wof_l, 256, wv << 5, 0, 16, a0, a1);
      float bv = bo_l[(wv << 5) + l31];
#pragma unroll
      for (int reg = 0; reg < 16; ++reg) {
        rs0[reg] += a0[reg] + bv;
        rs1[reg] += a1[reg] + bv;
      }
    }
    // NOTE: no barrier needed here — lnorm's dump overlays qS (last read at
    // attention, already barrier-protected); out-proj's kS reads are disjoint.
    lnorm(g1_all + (l << 8), be1_all + (l << 8));

    // ---------- FFN: 2 chunks of 512 hidden ----------
    {
#pragma unroll 1
      for (int ch = 0; ch < 2; ++ch) {
        // FFN1: 2 rounds, hidden tile t = r*8 + wv of this chunk, both windows
#pragma unroll 1
        for (int r = 0; r < 2; ++r) {
          int t = r * 8 + wv;                 // 0..15
          f32x16 h0 = zero16(), h1 = zero16();
          int ng = (ch << 9) + (t << 5);
          gemmDual(xb, 8, w1b_l, w1f_l, 256, ng, 0, 16, h0, h1);
          float bv1 = b1_l[ng + l31];
          int hcol = (t << 5) + l31;
#pragma unroll
          for (int reg = 0; reg < 16; ++reg) {
            kb[swzW(CROW(reg), hcol, 9)]      = f2bf(fmaxf(h0[reg] + bv1, 0.f));
            kb[swzW(32 + CROW(reg), hcol, 9)] = f2bf(fmaxf(h1[reg] + bv1, 0.f));
          }
        }
        __syncthreads();
        // FFN2: tile wv, both windows, K=512 of this chunk, into resid
        {
          f32x16 f0 = zero16(), f1 = zero16();
          gemmDual(kb, 9, w2b_l, w2f_l, 1024, wv << 5, ch << 9, 32, f0, f1);
#pragma unroll
          for (int reg = 0; reg < 16; ++reg) {
            rs0[reg] += f0[reg];
            rs1[reg] += f1[reg];
          }
        }
        __syncthreads();                      // kb reads retired before next write
      }
      float bv2 = b2_l[(wv << 5) + l31];
#pragma unroll
      for (int reg = 0; reg < 16; ++reg) { rs0[reg] += bv2; rs1[reg] += bv2; }
    }
    lnorm(g2_all + (l << 8), be2_all + (l << 8));
  }

  // ---------- head: logits from row 31 of each window ----------
  if (hi == 1) {
    int c = (wv << 5) + l31;
    hf[c]       = rs0[15];   // CROW(15)|hi=1 == row 31
    hf[256 + c] = rs1[15];
  }
  __syncthreads();
  if (wv < 2) {
    int c = l31;
    const float* hrow = hf + (wv << 8) + (hi << 7);
    const float* wrow = hw + (c << 8) + (hi << 7);
    float sum = 0.f;
#pragma unroll
    for (int i = 0; i < 128; i += 4) {
      f32x4 a = *(const f32x4*)(hrow + i);
      f32x4 b = *(const f32x4*)(wrow + i);
      sum += a[0]*b[0] + a[1]*b[1] + a[2]*b[2] + a[3]*b[3];
    }
    sum += __shfl_xor(sum, 32);
    if (hi == 0) out[(((size_t)blk * 2 + wv) << 5) + c] = sum + hb[c];
  }
}

extern "C" void kernel_launch(void* const* d_in, const int* in_sizes, int n_in,
                              void* d_out, int out_size, void* d_ws, size_t ws_size,
                              hipStream_t stream) {
  const float* X    = (const float*)d_in[0];
  const float* pos  = (const float*)d_in[3];
  const float* wq   = (const float*)d_in[4];
  const float* bq   = (const float*)d_in[5];
  const float* wo   = (const float*)d_in[6];
  const float* bo   = (const float*)d_in[7];
  const float* w1   = (const float*)d_in[8];
  const float* b1   = (const float*)d_in[9];
  const float* w2   = (const float*)d_in[10];
  const float* b2   = (const float*)d_in[11];
  const float* g1   = (const float*)d_in[12];
  const float* be1  = (const float*)d_in[13];
  const float* g2   = (const float*)d_in[14];
  const float* be2  = (const float*)d_in[15];
  const float* hw   = (const float*)d_in[16];
  const float* hb   = (const float*)d_in[17];
  float* out = (float*)d_out;

  const size_t nq = (size_t)CL * 768 * 256;
  const size_t no = (size_t)CL * 256 * 256;
  const size_t n1 = (size_t)CL * 1024 * 256;
  const size_t n2 = (size_t)CL * 256 * 1024;
  const size_t need = (nq + no + n1 + n2) * sizeof(short);

  short* wsq = (short*)d_ws;
  short* wso = wsq + nq;
  short* ws1 = wso + no;
  short* ws2 = ws1 + n1;

  const int nblk = 1024;   // 2048 windows / 2 per block

  if (ws_size >= need) {
    cvt_bf16<<<1024, 256, 0, stream>>>(wq, wsq, (int)nq);
    cvt_bf16<<<1024, 256, 0, stream>>>(wo, wso, (int)no);
    cvt_bf16<<<1024, 256, 0, stream>>>(w1, ws1, (int)n1);
    cvt_bf16<<<1024, 256, 0, stream>>>(w2, ws2, (int)n2);
    swt_fused<1><<<nblk, 512, 0, stream>>>(X, pos, wq, bq, wo, bo, w1, b1, w2, b2,
                                           g1, be1, g2, be2, hw, hb,
                                           wsq, wso, ws1, ws2, out);
  } else {
    swt_fused<0><<<nblk, 512, 0, stream>>>(X, pos, wq, bq, wo, bo, w1, b1, w2, b2,
                                           g1, be1, g2, be2, hw, hb,
                                           nullptr, nullptr, nullptr, nullptr, out);
  }
}

// Round 14
// 1018.537 us; speedup vs baseline: 1.5875x; 1.0005x over previous
//
#include <hip/hip_runtime.h>
#include <hip/hip_bf16.h>
#include <cstdint>
#include <cstddef>

typedef __attribute__((ext_vector_type(8))) short bf16x8;
typedef __attribute__((ext_vector_type(4))) float f32x4;
typedef __attribute__((ext_vector_type(16))) float f32x16;

constexpr int CL = 4;      // layers
constexpr int CS = 512;    // seq len

// fp32 -> bf16 RNE via HIP intrinsic (1 VALU op; correctness-verified r12)
__device__ __forceinline__ short f2bf(float f) {
  union { __hip_bfloat16 h; short s; } u;
  u.h = __float2bfloat16(f);
  return u.s;
}
__device__ __forceinline__ uint32_t pk2bf(float a, float b) {
  return (uint32_t)(uint16_t)f2bf(a) | ((uint32_t)(uint16_t)f2bf(b) << 16);
}
__device__ __forceinline__ f32x16 mfma32(bf16x8 a, bf16x8 b, f32x16 c) {
  return __builtin_amdgcn_mfma_f32_32x32x16_bf16(a, b, c, 0, 0, 0);
}
__device__ __forceinline__ f32x16 zero16() {
  f32x16 z;
#pragma unroll
  for (int i = 0; i < 16; ++i) z[i] = 0.f;
  return z;
}
// XOR swizzle: conflict-free for 32-row column-slice ds_read_b128.
__device__ __forceinline__ int swzW(int r, int c, int ldshift) {
  int g = (c >> 3) ^ (r & 7) ^ (((r >> 3) & 3) << 3);
  return (r << ldshift) + (g << 3) + (c & 7);
}

__global__ void cvt_bf16(const float* __restrict__ src, short* __restrict__ dst, int n) {
  int i = blockIdx.x * blockDim.x + threadIdx.x;
  int stride = gridDim.x * blockDim.x;
  for (; i < n; i += stride) dst[i] = f2bf(src[i]);
}

// B-fragment for mfma_f32_32x32x16 from row-major [N][K] weights.
template<int USEWS>
__device__ __forceinline__ bf16x8 ldB32(const short* __restrict__ wb,
                                        const float* __restrict__ wf,
                                        int ldk, int n0, int k0, int lane) {
  int n = n0 + (lane & 31);
  int k = k0 + ((lane >> 5) << 3);
  if constexpr (USEWS) {
    return *(const bf16x8*)&wb[(size_t)n * ldk + k];
  } else {
    const float* p = &wf[(size_t)n * ldk + k];
    f32x4 u = *(const f32x4*)p;
    f32x4 v = *(const f32x4*)(p + 4);
    bf16x8 r;
    r[0]=f2bf(u[0]); r[1]=f2bf(u[1]); r[2]=f2bf(u[2]); r[3]=f2bf(u[3]);
    r[4]=f2bf(v[0]); r[5]=f2bf(v[1]); r[6]=f2bf(v[2]); r[7]=f2bf(v[3]);
    return r;
  }
}

#define CROW(reg) ((((reg) & 3)) + ((((reg) >> 2)) << 3) + (hi << 2))

template<int USEWS>
__global__ __launch_bounds__(512, 2)
__attribute__((amdgpu_waves_per_eu(2, 2)))   // pin occupancy target: free the full 256-reg budget
void swt_fused(const float* __restrict__ X,
               const float* __restrict__ pos,
               const float* __restrict__ wqf, const float* __restrict__ bq_all,
               const float* __restrict__ wof, const float* __restrict__ bo_all,
               const float* __restrict__ w1f, const float* __restrict__ b1_all,
               const float* __restrict__ w2f, const float* __restrict__ b2_all,
               const float* __restrict__ g1_all, const float* __restrict__ be1_all,
               const float* __restrict__ g2_all, const float* __restrict__ be2_all,
               const float* __restrict__ hw, const float* __restrict__ hb,
               const short* __restrict__ wqb, const short* __restrict__ wob,
               const short* __restrict__ w1b, const short* __restrict__ w2b,
               float* __restrict__ out)
{
  __shared__ __align__(16) char arena[139776];
  short* xb = (short*)arena;                   // [64][256] swz bf16 x (both windows)
  short* qS = (short*)(arena + 32768);         // [64][256] swz : q
  short* kS = (short*)(arena + 65536);         // [64][256] swz : k -> o
  short* vt = (short*)(arena + 98304);         // [16][32][38] v^T per (win,head)
  float* lnM = (float*)(arena + 137216);       // [64][2] mu/rs
  float* hf  = (float*)(arena + 137728);       // [2][256] head input
  float* lnbuf = (float*)(arena + 32768);      // [64][260] overlay (LN dump / phase0)
  short* kb = (short*)(arena + 32768);         // [64][512] swz overlay (FFN hidden)

  const int tid = threadIdx.x;
  const int wv = tid >> 6;            // 0..7 = column octant
  const int lane = tid & 63;
  const int l31 = lane & 31;
  const int hi = lane >> 5;

  const int blk = blockIdx.x;

  // ---------- phase 0: build 2 windows (x + pos) ----------
  {
    int r = tid >> 3;                 // 0..63
    int c0 = (tid & 7) << 5;          // 32 floats per thread
    int wi0 = r >> 5, slot = r & 31;
    int g = (blk << 1) + wi0;
    int bb = g >> 9, ss = g & (CS - 1);
    int src = ss - slot; if (src < 0) src = 0;
    const float* Xr = X + (((size_t)(bb * CS + src)) << 8) + c0;
    const float* Pr = pos + (slot << 8) + c0;
#pragma unroll
    for (int m = 0; m < 4; ++m) {
      f32x4 x0 = *(const f32x4*)(Xr + m * 8);
      f32x4 x1 = *(const f32x4*)(Xr + m * 8 + 4);
      f32x4 p0 = *(const f32x4*)(Pr + m * 8);
      f32x4 p1 = *(const f32x4*)(Pr + m * 8 + 4);
      f32x4 s0, s1;
      bf16x8 pkv;
#pragma unroll
      for (int j = 0; j < 4; ++j) { s0[j] = x0[j] + p0[j]; pkv[j] = f2bf(s0[j]); }
#pragma unroll
      for (int j = 0; j < 4; ++j) { s1[j] = x1[j] + p1[j]; pkv[4 + j] = f2bf(s1[j]); }
      *(f32x4*)&lnbuf[r * 260 + c0 + m * 8] = s0;
      *(f32x4*)&lnbuf[r * 260 + c0 + m * 8 + 4] = s1;
      *(bf16x8*)&xb[swzW(r, c0 + m * 8, 8)] = pkv;
    }
  }
  __syncthreads();

  // residual registers for BOTH windows: win0 rows CROW, win1 rows 32+CROW; col 32*wv+l31
  f32x16 rs0, rs1;
  {
    int c = (wv << 5) + l31;
#pragma unroll
    for (int reg = 0; reg < 16; ++reg) {
      rs0[reg] = lnbuf[(CROW(reg)) * 260 + c];
      rs1[reg] = lnbuf[(32 + CROW(reg)) * 260 + c];
    }
  }
  __syncthreads();

  // dual-window gemm: 2 mfma per B-load (A rows l31 and 32+l31), 8-deep in-flight B
  auto gemmDual = [&](const short* Abuf, int ldshift,
                      const short* wb, const float* wf, int ldk,
                      int bn0, int kB, int nsteps, f32x16& acc0, f32x16& acc1) {
#pragma unroll 8
    for (int kk = 0; kk < nsteps; ++kk) {
      bf16x8 A0 = *(const bf16x8*)&Abuf[swzW(l31,      (kk << 4) + (hi << 3), ldshift)];
      bf16x8 A1 = *(const bf16x8*)&Abuf[swzW(32 + l31, (kk << 4) + (hi << 3), ldshift)];
      bf16x8 B = ldB32<USEWS>(wb, wf, ldk, bn0, kB + (kk << 4), lane);
      acc0 = mfma32(A0, B, acc0);
      acc1 = mfma32(A1, B, acc1);
    }
  };

  auto lnorm = [&](const float* g, const float* be) {
    int c = (wv << 5) + l31;
#pragma unroll
    for (int reg = 0; reg < 16; ++reg) {
      lnbuf[(CROW(reg)) * 260 + c]      = rs0[reg];
      lnbuf[(32 + CROW(reg)) * 260 + c] = rs1[reg];
    }
    __syncthreads();
    {
      int r = tid >> 3, sub = tid & 7;
      float s1 = 0.f, s2 = 0.f;
#pragma unroll
      for (int i = 0; i < 32; ++i) {
        float v = lnbuf[r * 260 + sub + (i << 3)];
        s1 += v; s2 += v * v;
      }
#pragma unroll
      for (int d = 1; d < 8; d <<= 1) { s1 += __shfl_xor(s1, d); s2 += __shfl_xor(s2, d); }
      if (sub == 0) {
        float mu = s1 * (1.f / 256.f);
        float var = s2 * (1.f / 256.f) - mu * mu;
        lnM[r * 2] = mu;
        lnM[r * 2 + 1] = rsqrtf(var + 1e-5f);
      }
    }
    __syncthreads();
    {
      float gv = g[c], bv = be[c];
#pragma unroll
      for (int reg = 0; reg < 16; ++reg) {
        int R0 = CROW(reg), R1 = 32 + R0;
        float v0 = (rs0[reg] - lnM[R0 * 2]) * lnM[R0 * 2 + 1] * gv + bv;
        float v1 = (rs1[reg] - lnM[R1 * 2]) * lnM[R1 * 2 + 1] * gv + bv;
        rs0[reg] = v0;
        rs1[reg] = v1;
        xb[swzW(R0, c, 8)] = f2bf(v0);
        xb[swzW(R1, c, 8)] = f2bf(v1);
      }
    }
    __syncthreads();
  };

  const float scale = 0.17677669529663687f;  // 1/sqrt(32)

#pragma unroll 1
  for (int l = 0; l < CL; ++l) {
    const short* wqb_l = wqb + (size_t)l * 768 * 256;
    const float* wqf_l = wqf + (size_t)l * 768 * 256;
    const float* bq_l  = bq_all + l * 768;
    const short* wob_l = wob + (size_t)l * 256 * 256;
    const float* wof_l = wof + (size_t)l * 256 * 256;
    const float* bo_l  = bo_all + l * 256;
    const short* w1b_l = w1b + (size_t)l * 1024 * 256;
    const float* w1f_l = w1f + (size_t)l * 1024 * 256;
    const float* b1_l  = b1_all + l * 1024;
    const short* w2b_l = w2b + (size_t)l * 256 * 1024;
    const float* w2f_l = w2f + (size_t)l * 256 * 1024;
    const float* b2_l  = b2_all + l * 256;

    // ---------- QKV: 3 rounds, tile t = r*8 + wv, both windows per job ----------
#pragma unroll 1
    for (int r = 0; r < 3; ++r) {
      int t = r * 8 + wv;                     // 0..23
      f32x16 a0 = zero16(), a1 = zero16();
      gemmDual(xb, 8, wqb_l, wqf_l, 256, t << 5, 0, 16, a0, a1);
      float bv = bq_l[(t << 5) + l31];
      if (t < 8) {                            // q (pre-scaled)
        int col = (t << 5) + l31;
#pragma unroll
        for (int reg = 0; reg < 16; ++reg) {
          qS[swzW(CROW(reg), col, 8)]      = f2bf((a0[reg] + bv) * scale);
          qS[swzW(32 + CROW(reg), col, 8)] = f2bf((a1[reg] + bv) * scale);
        }
      } else if (t < 16) {                    // k
        int col = ((t - 8) << 5) + l31;
#pragma unroll
        for (int reg = 0; reg < 16; ++reg) {
          kS[swzW(CROW(reg), col, 8)]      = f2bf(a0[reg] + bv);
          kS[swzW(32 + CROW(reg), col, 8)] = f2bf(a1[reg] + bv);
        }
      } else {                                // v -> v^T per (win, head)
        int h = t - 16;
        short* vr0 = &vt[((size_t)(h)     * 32 + l31) * 38];
        short* vr1 = &vt[((size_t)(8 + h) * 32 + l31) * 38];
#pragma unroll
        for (int reg = 0; reg < 16; ++reg) {
          vr0[CROW(reg)] = f2bf(a0[reg] + bv);
          vr1[CROW(reg)] = f2bf(a1[reg] + bv);
        }
      }
    }
    __syncthreads();

    // ---------- attention: head = wv, both windows (interleaved chains) ----------
#pragma unroll
    for (int wi2 = 0; wi2 < 2; ++wi2) {
      int ar = wi2 << 5;
      int hc = wv << 5;
      f32x16 st = zero16();
#pragma unroll
      for (int ks = 0; ks < 2; ++ks) {
        bf16x8 ak = *(const bf16x8*)&kS[swzW(ar + l31, hc + (ks << 4) + (hi << 3), 8)];
        bf16x8 bq_ = *(const bf16x8*)&qS[swzW(ar + l31, hc + (ks << 4) + (hi << 3), 8)];
        st = mfma32(ak, bq_, st);   // S^T[tok][q]
      }
      float m = st[0];
#pragma unroll
      for (int reg = 1; reg < 16; ++reg) m = fmaxf(m, st[reg]);
      m = fmaxf(m, __shfl_xor(m, 32));
      float s = 0.f;
#pragma unroll
      for (int reg = 0; reg < 16; ++reg) { st[reg] = __expf(st[reg] - m); s += st[reg]; }
      s += __shfl_xor(s, 32);
      float inv = 1.0f / s;
#pragma unroll
      for (int reg = 0; reg < 16; ++reg) st[reg] *= inv;

      f32x16 ot = zero16();
#pragma unroll
      for (int ks = 0; ks < 2; ++ks) {
        uint32_t a0 = pk2bf(st[ks * 8 + 0], st[ks * 8 + 1]);
        uint32_t a1 = pk2bf(st[ks * 8 + 2], st[ks * 8 + 3]);
        uint32_t b0 = pk2bf(st[ks * 8 + 4], st[ks * 8 + 5]);
        uint32_t b1 = pk2bf(st[ks * 8 + 6], st[ks * 8 + 7]);
        uint32_t sa0 = __shfl_xor(a0, 32);
        uint32_t sa1 = __shfl_xor(a1, 32);
        uint32_t sb0 = __shfl_xor(b0, 32);
        uint32_t sb1 = __shfl_xor(b1, 32);
        union { uint32_t u[4]; bf16x8 v; } pf;
        pf.u[0] = hi ? sb0 : a0;
        pf.u[1] = hi ? sb1 : a1;
        pf.u[2] = hi ? b0 : sa0;
        pf.u[3] = hi ? b1 : sa1;
        bf16x8 av = *(const bf16x8*)&vt[(((wi2 << 3) + wv) * 32 + l31) * 38 + (ks << 4) + (hi << 3)];
        ot = mfma32(av, pf.v, ot);  // O^T[dh][q]
      }
#pragma unroll
      for (int reg = 0; reg < 16; ++reg)
        kS[swzW(ar + l31, hc + CROW(reg), 8)] = f2bf(ot[reg]);
    }
    __syncthreads();

    // ---------- output projection: tile wv, both windows, K=256 ----------
    {
      f32x16 a0 = zero16(), a1 = zero16();
      gemmDual(kS, 8, wob_l, wof_l, 256, wv << 5, 0, 16, a0, a1);
      float bv = bo_l[(wv << 5) + l31];
#pragma unroll
      for (int reg = 0; reg < 16; ++reg) {
        rs0[reg] += a0[reg] + bv;
        rs1[reg] += a1[reg] + bv;
      }
    }
    // NOTE: no barrier needed here — lnorm's dump overlays qS (last read at
    // attention, already barrier-protected); out-proj's kS reads are disjoint.
    lnorm(g1_all + (l << 8), be1_all + (l << 8));

    // ---------- FFN: 2 chunks of 512 hidden ----------
    {
#pragma unroll 1
      for (int ch = 0; ch < 2; ++ch) {
        // FFN1: 2 rounds, hidden tile t = r*8 + wv of this chunk, both windows
#pragma unroll 1
        for (int r = 0; r < 2; ++r) {
          int t = r * 8 + wv;                 // 0..15
          f32x16 h0 = zero16(), h1 = zero16();
          int ng = (ch << 9) + (t << 5);
          gemmDual(xb, 8, w1b_l, w1f_l, 256, ng, 0, 16, h0, h1);
          float bv1 = b1_l[ng + l31];
          int hcol = (t << 5) + l31;
#pragma unroll
          for (int reg = 0; reg < 16; ++reg) {
            kb[swzW(CROW(reg), hcol, 9)]      = f2bf(fmaxf(h0[reg] + bv1, 0.f));
            kb[swzW(32 + CROW(reg), hcol, 9)] = f2bf(fmaxf(h1[reg] + bv1, 0.f));
          }
        }
        __syncthreads();
        // FFN2: tile wv, both windows, K=512 of this chunk, into resid
        {
          f32x16 f0 = zero16(), f1 = zero16();
          gemmDual(kb, 9, w2b_l, w2f_l, 1024, wv << 5, ch << 9, 32, f0, f1);
#pragma unroll
          for (int reg = 0; reg < 16; ++reg) {
            rs0[reg] += f0[reg];
            rs1[reg] += f1[reg];
          }
        }
        __syncthreads();                      // kb reads retired before next write
      }
      float bv2 = b2_l[(wv << 5) + l31];
#pragma unroll
      for (int reg = 0; reg < 16; ++reg) { rs0[reg] += bv2; rs1[reg] += bv2; }
    }
    lnorm(g2_all + (l << 8), be2_all + (l << 8));
  }

  // ---------- head: logits from row 31 of each window ----------
  if (hi == 1) {
    int c = (wv << 5) + l31;
    hf[c]       = rs0[15];   // CROW(15)|hi=1 == row 31
    hf[256 + c] = rs1[15];
  }
  __syncthreads();
  if (wv < 2) {
    int c = l31;
    const float* hrow = hf + (wv << 8) + (hi << 7);
    const float* wrow = hw + (c << 8) + (hi << 7);
    float sum = 0.f;
#pragma unroll
    for (int i = 0; i < 128; i += 4) {
      f32x4 a = *(const f32x4*)(hrow + i);
      f32x4 b = *(const f32x4*)(wrow + i);
      sum += a[0]*b[0] + a[1]*b[1] + a[2]*b[2] + a[3]*b[3];
    }
    sum += __shfl_xor(sum, 32);
    if (hi == 0) out[(((size_t)blk * 2 + wv) << 5) + c] = sum + hb[c];
  }
}

extern "C" void kernel_launch(void* const* d_in, const int* in_sizes, int n_in,
                              void* d_out, int out_size, void* d_ws, size_t ws_size,
                              hipStream_t stream) {
  const float* X    = (const float*)d_in[0];
  const float* pos  = (const float*)d_in[3];
  const float* wq   = (const float*)d_in[4];
  const float* bq   = (const float*)d_in[5];
  const float* wo   = (const float*)d_in[6];
  const float* bo   = (const float*)d_in[7];
  const float* w1   = (const float*)d_in[8];
  const float* b1   = (const float*)d_in[9];
  const float* w2   = (const float*)d_in[10];
  const float* b2   = (const float*)d_in[11];
  const float* g1   = (const float*)d_in[12];
  const float* be1  = (const float*)d_in[13];
  const float* g2   = (const float*)d_in[14];
  const float* be2  = (const float*)d_in[15];
  const float* hw   = (const float*)d_in[16];
  const float* hb   = (const float*)d_in[17];
  float* out = (float*)d_out;

  const size_t nq = (size_t)CL * 768 * 256;
  const size_t no = (size_t)CL * 256 * 256;
  const size_t n1 = (size_t)CL * 1024 * 256;
  const size_t n2 = (size_t)CL * 256 * 1024;
  const size_t need = (nq + no + n1 + n2) * sizeof(short);

  short* wsq = (short*)d_ws;
  short* wso = wsq + nq;
  short* ws1 = wso + no;
  short* ws2 = ws1 + n1;

  const int nblk = 1024;   // 2048 windows / 2 per block

  if (ws_size >= need) {
    cvt_bf16<<<1024, 256, 0, stream>>>(wq, wsq, (int)nq);
    cvt_bf16<<<1024, 256, 0, stream>>>(wo, wso, (int)no);
    cvt_bf16<<<1024, 256, 0, stream>>>(w1, ws1, (int)n1);
    cvt_bf16<<<1024, 256, 0, stream>>>(w2, ws2, (int)n2);
    swt_fused<1><<<nblk, 512, 0, stream>>>(X, pos, wq, bq, wo, bo, w1, b1, w2, b2,
                                           g1, be1, g2, be2, hw, hb,
                                           wsq, wso, ws1, ws2, out);
  } else {
    swt_fused<0><<<nblk, 512, 0, stream>>>(X, pos, wq, bq, wo, bo, w1, b1, w2, b2,
                                           g1, be1, g2, be2, hw, hb,
                                           nullptr, nullptr, nullptr, nullptr, out);
  }
}